// Round 1
// baseline (4718.164 us; speedup 1.0000x reference)
//
#include <hip/hip_runtime.h>
#include <math.h>

#define B 8
#define CIN 64
#define COUT 64
#define H 512
#define W 512
#define KS 3

#define TH 16
#define TW 16
#define CI_BLK 16
#define CO_BLK 32   // 2 co-groups of 32; 32 accumulators/thread

// ---------------------------------------------------------------------------
// Kernel 1: modulate + demodulate the shared 3x3 kernel per (b, co).
// grid = B*COUT blocks, 64 threads (1 wave). Thread ci handles one input
// channel's 9 taps; xor-butterfly reduces sum-of-squares across the wave.
// ---------------------------------------------------------------------------
__global__ __launch_bounds__(64) void modw_kernel(const float* __restrict__ w,
                                                  const float* __restrict__ weight,
                                                  float* __restrict__ wm) {
  int b  = blockIdx.x >> 6;
  int co = blockIdx.x & 63;
  int ci = threadIdx.x;
  const float scale = 1.0f / 24.0f;  // 1/sqrt(CIN*K*K) = 1/sqrt(576)
  float wv = w[b * CIN + ci] * scale;
  const float* wp = weight + ((size_t)co * CIN + ci) * 9;
  float v[9];
  float ss = 0.f;
#pragma unroll
  for (int j = 0; j < 9; j++) {
    v[j] = wp[j] * wv;
    ss = fmaf(v[j], v[j], ss);
  }
#pragma unroll
  for (int off = 32; off > 0; off >>= 1) ss += __shfl_xor(ss, off, 64);
  float d = 1.0f / sqrtf(ss + 1e-8f);
  float* op = wm + (((size_t)b * COUT + co) * CIN + ci) * 9;
#pragma unroll
  for (int j = 0; j < 9; j++) op[j] = v[j] * d;
}

// ---------------------------------------------------------------------------
// Kernel 2: direct conv. Block = 16x16 output tile for one (b, co-group of 32).
// x tile (18x18 halo) staged in LDS per 16-channel chunk; weights read via
// block-uniform addresses (expect s_load -> SGPR operands to v_fmac).
// ---------------------------------------------------------------------------
__global__ __launch_bounds__(256) void conv_kernel(const float* __restrict__ x,
                                                   const float* __restrict__ wm,
                                                   float* __restrict__ y) {
  const int bx = blockIdx.x;           // W tile
  const int by = blockIdx.y;           // H tile
  const int bz = blockIdx.z;           // b * (COUT/CO_BLK) + co_group
  const int b   = bz >> 1;
  const int co0 = (bz & 1) * CO_BLK;

  const int x0 = bx * TW;
  const int y0 = by * TH;
  const int tid = threadIdx.x;
  const int tx = tid & (TW - 1);
  const int ty = tid >> 4;

  __shared__ float sx[CI_BLK * 18 * 18];

  float acc[CO_BLK];
#pragma unroll
  for (int c = 0; c < CO_BLK; c++) acc[c] = 0.f;

  const float* xb = x + (size_t)b * CIN * H * W;
  const float* wb = wm + ((size_t)b * COUT + co0) * CIN * 9;

  for (int ci0 = 0; ci0 < CIN; ci0 += CI_BLK) {
    __syncthreads();
    // ---- stage 18x18 halo tile for CI_BLK channels ----
    for (int idx = tid; idx < CI_BLK * 18 * 18; idx += 256) {
      int ci  = idx / 324;
      int rem = idx - ci * 324;
      int yy  = rem / 18;
      int xx  = rem - yy * 18;
      int gy = y0 + yy - 1;
      int gx = x0 + xx - 1;
      float v = 0.f;
      if ((unsigned)gy < (unsigned)H && (unsigned)gx < (unsigned)W)
        v = xb[((size_t)(ci0 + ci) * H + gy) * W + gx];
      sx[idx] = v;
    }
    __syncthreads();

    // ---- compute ----
    for (int ci = 0; ci < CI_BLK; ci++) {
      float xv[3][3];
#pragma unroll
      for (int kh = 0; kh < 3; kh++)
#pragma unroll
        for (int kw = 0; kw < 3; kw++)
          xv[kh][kw] = sx[ci * 324 + (ty + kh) * 18 + (tx + kw)];

      const float* wp = wb + (size_t)(ci0 + ci) * 9;  // + c*CIN*9 per co
#pragma unroll
      for (int c = 0; c < CO_BLK; c++) {
        const float* wcp = wp + (size_t)c * CIN * 9;
#pragma unroll
        for (int kh = 0; kh < 3; kh++)
#pragma unroll
          for (int kw = 0; kw < 3; kw++)
            acc[c] = fmaf(xv[kh][kw], wcp[kh * 3 + kw], acc[c]);
      }
    }
  }

  // ---- write out ----
  size_t obase = (((size_t)b * COUT + co0) * H + (y0 + ty)) * W + (x0 + tx);
#pragma unroll
  for (int c = 0; c < CO_BLK; c++)
    y[obase + (size_t)c * H * W] = acc[c];
}

extern "C" void kernel_launch(void* const* d_in, const int* in_sizes, int n_in,
                              void* d_out, int out_size, void* d_ws, size_t ws_size,
                              hipStream_t stream) {
  const float* x      = (const float*)d_in[0];   // [B, CIN, H, W]
  const float* w      = (const float*)d_in[1];   // [B, CIN]
  const float* weight = (const float*)d_in[2];   // [COUT, CIN, 3, 3]
  float* y  = (float*)d_out;                     // [B, COUT, H, W]
  float* wm = (float*)d_ws;                      // B*COUT*CIN*9 floats = 1.18 MB

  modw_kernel<<<B * COUT, 64, 0, stream>>>(w, weight, wm);

  dim3 grid(W / TW, H / TH, B * (COUT / CO_BLK));
  conv_kernel<<<grid, 256, 0, stream>>>(x, wm, y);
}